// Round 5
// baseline (300.605 us; speedup 1.0000x reference)
//
#include <hip/hip_runtime.h>
#include <hip/hip_bf16.h>

typedef short short8 __attribute__((ext_vector_type(8)));
typedef float f32x4 __attribute__((ext_vector_type(4)));
typedef unsigned short ushort_t;

#define AS1 __attribute__((address_space(1)))
#define AS3 __attribute__((address_space(3)))

__device__ __forceinline__ ushort_t f2bf(float f) {
    unsigned u = __builtin_bit_cast(unsigned, f);
    unsigned r = (u + 0x7FFFu + ((u >> 16) & 1u)) >> 16;
    return (ushort_t)r;
}

// -------------------------------------------------------------------------
// K0: zero the top/bottom padded border rows of x_t [16][258][258][64]
// -------------------------------------------------------------------------
__global__ __launch_bounds__(256) void dc_k0_zeroborder(ushort_t* __restrict__ x_t)
{
    const int b = blockIdx.x, t = threadIdx.x;
    const int n = b >> 1, row = (b & 1) ? 257 : 0;
    short8 z = {0, 0, 0, 0, 0, 0, 0, 0};
    short8* p = reinterpret_cast<short8*>(x_t + (size_t)(n * 258 + row) * 258 * 64);
    for (int i = t; i < 2064; i += 256) p[i] = z;  // 258*64/8
}

// -------------------------------------------------------------------------
// K1: per (n, row h): stage x[n][:, h, :] as bf16 [256px][64c] in LDS
// (XOR-swizzled), (a) write padded-NHWC bf16 x_t (+ zero col borders),
// (b) attention dot via MFMA: s[n][d] += sum_px relu(w1[d,:]·x[:,px]+b1[d])
// -------------------------------------------------------------------------
__global__ __launch_bounds__(256) void dc_k1_stage_attn(
    const float* __restrict__ x, const float* __restrict__ w1,
    const float* __restrict__ b1, float* __restrict__ s_glob,
    ushort_t* __restrict__ x_t)
{
    __shared__ unsigned xt32[256 * 32];   // 256 px * 64c bf16, swizzled
    __shared__ ushort_t w1s[16 * 64];
    __shared__ float sacc[16];

    const int n = blockIdx.y, h = blockIdx.x, t = threadIdx.x;
    if (t < 16) sacc[t] = 0.f;
#pragma unroll
    for (int q = 0; q < 4; ++q) { int idx = q * 256 + t; w1s[idx] = f2bf(w1[idx]); }

    const float* xr = x + ((size_t)n * 64) * 65536 + (size_t)h * 256;
    const int sw = (t & 7) << 2;
    for (int cp = 0; cp < 32; ++cp) {
        float a = xr[(size_t)(2 * cp) * 65536 + t];
        float b = xr[(size_t)(2 * cp + 1) * 65536 + t];
        xt32[(t * 32 + cp) ^ sw] = (unsigned)f2bf(a) | ((unsigned)f2bf(b) << 16);
    }
    __syncthreads();

    const int lane = t & 63, wv = t >> 6, l15 = lane & 15, lg = lane >> 4;
    const short8* xt8 = reinterpret_cast<const short8*>(xt32);
    const short8* w18 = reinterpret_cast<const short8*>(w1s);

    short8 a0 = w18[l15 * 8 + lg];
    short8 a1 = w18[l15 * 8 + 4 + lg];
    float b1v[4];
#pragma unroll
    for (int r = 0; r < 4; ++r) b1v[r] = b1[lg * 4 + r];

    float rs[4] = {0.f, 0.f, 0.f, 0.f};
#pragma unroll
    for (int q = 0; q < 4; ++q) {
        int px = (wv * 4 + q) * 16 + l15;
        int pb = px * 8, ps = px & 7;
        short8 bb0 = xt8[pb + (lg ^ ps)];
        short8 bb1 = xt8[pb + ((4 + lg) ^ ps)];
        f32x4 hacc = {0.f, 0.f, 0.f, 0.f};
        hacc = __builtin_amdgcn_mfma_f32_16x16x32_bf16(a0, bb0, hacc, 0, 0, 0);
        hacc = __builtin_amdgcn_mfma_f32_16x16x32_bf16(a1, bb1, hacc, 0, 0, 0);
#pragma unroll
        for (int r = 0; r < 4; ++r) rs[r] += fmaxf(hacc[r] + b1v[r], 0.f);
    }
#pragma unroll
    for (int off = 1; off < 16; off <<= 1)
#pragma unroll
        for (int r = 0; r < 4; ++r) rs[r] += __shfl_xor(rs[r], off);
    if (l15 == 0) {
#pragma unroll
        for (int r = 0; r < 4; ++r) atomicAdd(&sacc[lg * 4 + r], rs[r]);
    }
    __syncthreads();
    if (t < 16) atomicAdd(&s_glob[n * 16 + t], sacc[t]);

    // write-out padded NHWC bf16 (interior cols 1..256 of padded row h+1)
    ushort_t* xo = x_t + (((size_t)n * 258 + h + 1) * 258 + 1) * 64;
    const int cb = t & 7, pxr = t >> 3;
#pragma unroll
    for (int rr = 0; rr < 8; ++rr) {
        int px = rr * 32 + pxr;
        short8 v = xt8[px * 8 + (cb ^ (px & 7))];
        *reinterpret_cast<short8*>(xo + (size_t)px * 64 + cb * 8) = v;
    }
    // zero the left/right padded columns of this row
    if (t < 16) {
        short8 z = {0, 0, 0, 0, 0, 0, 0, 0};
        size_t colbase = (((size_t)n * 258 + h + 1) * 258 + ((t < 8) ? 0 : 257)) * 64;
        reinterpret_cast<short8*>(x_t + colbase)[t & 7] = z;
    }
}

// -------------------------------------------------------------------------
// K2a: s -> pooled -> softmax(pi) ; aggregate bias b_agg[n][o]
// -------------------------------------------------------------------------
__global__ void dc_k2a_softmax_bias(
    const float* __restrict__ s_glob, const float* __restrict__ w2,
    const float* __restrict__ b2, const float* __restrict__ b_bank,
    float* __restrict__ pi, float* __restrict__ b_agg)
{
    __shared__ float piL[16][4];
    const int t = threadIdx.x;
    if (t < 16) {
        int n = t;
        float z[4];
#pragma unroll
        for (int e = 0; e < 4; ++e) {
            float p = 0.f;
            for (int d = 0; d < 16; ++d) p += w2[e * 16 + d] * s_glob[n * 16 + d];
            z[e] = (b2[e] + p * (1.f / 65536.f)) * (1.f / 30.f);
        }
        float m = fmaxf(fmaxf(z[0], z[1]), fmaxf(z[2], z[3]));
        float ex[4], sum = 0.f;
#pragma unroll
        for (int e = 0; e < 4; ++e) { ex[e] = expf(z[e] - m); sum += ex[e]; }
        float inv = 1.f / sum;
#pragma unroll
        for (int e = 0; e < 4; ++e) { float v = ex[e] * inv; pi[n * 4 + e] = v; piL[n][e] = v; }
    }
    __syncthreads();
    for (int r = 0; r < 16; ++r) {
        float v = 0.f;
#pragma unroll
        for (int kw = 0; kw < 4; ++kw) v += piL[r][kw] * b_bank[t * 4 + kw];
        b_agg[r * 64 + t] = v;
    }
}

// -------------------------------------------------------------------------
// K2b: aggregate weights -> fragment-major A_frag[n][ks=ij*2+cc][mf][lane][8]
// -------------------------------------------------------------------------
__global__ void dc_k2b_aggw(const float* __restrict__ w_bank,
                            const float* __restrict__ pi,
                            ushort_t* __restrict__ A_frag)
{
    __shared__ float lw[2304];  // one o-row: [4 kw][64 c][9 ij]
    const int o = blockIdx.x, n = blockIdx.y, t = threadIdx.x;  // 64 threads
    const float* wrow = w_bank + (size_t)o * 2304;
    for (int rr = 0; rr < 36; ++rr) lw[rr * 64 + t] = wrow[rr * 64 + t];
    float p0 = pi[n * 4 + 0], p1 = pi[n * 4 + 1], p2 = pi[n * 4 + 2], p3 = pi[n * 4 + 3];
    __syncthreads();
    const int c = t;
    const int cc = c >> 5, lg = (c >> 3) & 3, e = c & 7;
    const int mf = o >> 4, l15 = o & 15;
    ushort_t* base = A_frag + (size_t)n * 18 * 4 * 64 * 8;
#pragma unroll
    for (int ij = 0; ij < 9; ++ij) {
        float v = p0 * lw[0 * 576 + c * 9 + ij] + p1 * lw[1 * 576 + c * 9 + ij]
                + p2 * lw[2 * 576 + c * 9 + ij] + p3 * lw[3 * 576 + c * 9 + ij];
        int ks = ij * 2 + cc;
        base[(((ks * 4 + mf) * 64) + (lg * 16 + l15)) * 8 + e] = f2bf(v);
    }
}

// -------------------------------------------------------------------------
// K3: implicit-GEMM conv, 2 output rows per block. ZERO LDS, ZERO BARRIERS.
// Block = (n, h0, 128-px half-row), 4 waves; wave = 64 Co x 32 px x 2 rows.
// B-fragments: direct global reads from padded x_t via 4 per-wave row
// pointers + immediate offsets (cc pair consumes full 128B lines; jo/nf
// re-touches hit L1). A-fragments: direct global (wave-identical addrs ->
// L1 broadcast). Rolling static register windows: B fixed-slot 4-ring,
// A 2-deep; prefetch distance 1 step (~310 SIMD-cyc) >> L2 latency.
// 3 blocks/CU via launch_bounds(256,3) -> 12 self-paced waves/CU.
// -------------------------------------------------------------------------
__global__ __launch_bounds__(256, 3) void dc_k3_conv(
    const ushort_t* __restrict__ x_t, const ushort_t* __restrict__ A_frag,
    const float* __restrict__ b_agg, float* __restrict__ out)
{
    int bid = blockIdx.x;
    int nb = (bid & 7) * 512 + (bid >> 3);   // XCD-chunked swizzle
    const int n = nb >> 8;
    const int tile = nb & 255;
    const int h0 = (tile >> 1) << 1;         // output rows h0, h0+1
    const int w0 = (tile & 1) << 7;

    const int t = threadIdx.x, lane = t & 63, wv = t >> 6;
    const int l15 = lane & 15, lg = lane >> 4;
    const int pxl = wv * 32;

    // per-lane row base pointers into padded x_t (row h0+r, col w0+pxl+l15)
    const char* xr0 = (const char*)x_t
        + (((size_t)n * 258 + h0) * 258 + (w0 + pxl + l15)) * 128 + lg * 16;
    const char* xr1 = xr0 + 33024;
    const char* xr2 = xr0 + 66048;
    const char* xr3 = xr0 + 99072;
    // offsets within a row: (nf*16 + jcol)*128 + cc*64   (max 2368 < 4096 imm)

    const char* Ab = (const char*)A_frag + (size_t)n * 73728 + lane * 16;
    // step ks: Ab + ks*4096 + mf*1024

    f32x4 acc[4][2][2] = {};
    short8 bwin[4][2];   // fixed slots: slot r = current group's input row r
    short8 af[2][4];

    // ---- initial loads: A(s=0, ks=0) + B group 0 rows 0,1 ----
#pragma unroll
    for (int mf = 0; mf < 4; ++mf)
        af[0][mf] = *reinterpret_cast<const short8*>(Ab + mf * 1024);
#pragma unroll
    for (int nf = 0; nf < 2; ++nf) {
        bwin[0][nf] = *reinterpret_cast<const short8*>(xr0 + nf * 2048);
        bwin[1][nf] = *reinterpret_cast<const short8*>(xr1 + nf * 2048);
    }

#pragma unroll
    for (int g = 0; g < 6; ++g) {            // group = (jcol = g>>1, cc = g&1)
        const int jcol = g >> 1, cc = g & 1;
        const int coff = jcol * 128 + cc * 64;
#pragma unroll
        for (int ir = 0; ir < 3; ++ir) {
            const int s = g * 3 + ir;
            // --- prefetch A for step s+1 ---
            if (s < 17) {
                const int s1 = s + 1;
                const int jc1 = s1 / 3, ir1 = s1 % 3;
                const int ks1 = (ir1 * 3 + (jc1 >> 1)) * 2 + (jc1 & 1);
                const char* Ap = Ab + ks1 * 4096;
#pragma unroll
                for (int mf = 0; mf < 4; ++mf)
                    af[s1 & 1][mf] = *reinterpret_cast<const short8*>(Ap + mf * 1024);
            }
            // --- prefetch B (fixed-slot ring) ---
            if (ir == 0) {
#pragma unroll
                for (int nf = 0; nf < 2; ++nf)
                    bwin[2][nf] = *reinterpret_cast<const short8*>(
                        xr2 + coff + nf * 2048);
            } else if (ir == 1) {
#pragma unroll
                for (int nf = 0; nf < 2; ++nf)
                    bwin[3][nf] = *reinterpret_cast<const short8*>(
                        xr3 + coff + nf * 2048);
            } else if (g < 5) {
                const int gn = g + 1;
                const int coffn = (gn >> 1) * 128 + (gn & 1) * 64;
#pragma unroll
                for (int nf = 0; nf < 2; ++nf) {
                    bwin[0][nf] = *reinterpret_cast<const short8*>(
                        xr0 + coffn + nf * 2048);
                    bwin[1][nf] = *reinterpret_cast<const short8*>(
                        xr1 + coffn + nf * 2048);
                }
            }
            // --- 16 MFMAs: uses bwin slots ir, ir+1 ---
#pragma unroll
            for (int mf = 0; mf < 4; ++mf)
#pragma unroll
                for (int nf = 0; nf < 2; ++nf)
#pragma unroll
                    for (int o = 0; o < 2; ++o)
                        acc[mf][nf][o] = __builtin_amdgcn_mfma_f32_16x16x32_bf16(
                            af[s & 1][mf], bwin[ir + o][nf], acc[mf][nf][o], 0, 0, 0);
        }
    }

    const float* bn = b_agg + n * 64;
#pragma unroll
    for (int mf = 0; mf < 4; ++mf) {
#pragma unroll
        for (int r = 0; r < 4; ++r) {
            const float bval = bn[mf * 16 + lg * 4 + r];
#pragma unroll
            for (int o = 0; o < 2; ++o)
#pragma unroll
                for (int nf = 0; nf < 2; ++nf) {
                    const int col = w0 + pxl + nf * 16 + l15;
                    const size_t base = ((size_t)(n * 64 + mf * 16 + lg * 4 + r) << 16)
                                        + (size_t)(h0 + o) * 256 + col;
                    out[base] = acc[mf][nf][o][r] + bval;
                }
        }
    }
}

// -------------------------------------------------------------------------
extern "C" void kernel_launch(void* const* d_in, const int* in_sizes, int n_in,
                              void* d_out, int out_size, void* d_ws, size_t ws_size,
                              hipStream_t stream) {
    const float* x      = (const float*)d_in[0];
    const float* w_bank = (const float*)d_in[1];
    const float* b_bank = (const float*)d_in[2];
    const float* att_w1 = (const float*)d_in[3];
    const float* att_b1 = (const float*)d_in[4];
    const float* att_w2 = (const float*)d_in[5];
    const float* att_b2 = (const float*)d_in[6];
    float* out = (float*)d_out;

    char* ws = (char*)d_ws;
    float*    s_glob = (float*)ws;                     // 1 KB
    float*    pi     = (float*)(ws + 1024);            // 256 B
    float*    b_agg  = (float*)(ws + 2048);            // 4 KB
    ushort_t* A_frag = (ushort_t*)(ws + 8192);         // 1.125 MB
    ushort_t* x_t    = (ushort_t*)(ws + (2ull << 20)); // padded NHWC bf16, ~136.3 MB

    hipMemsetAsync(s_glob, 0, 16 * 16 * sizeof(float), stream);

    dc_k0_zeroborder<<<32, 256, 0, stream>>>(x_t);
    dc_k1_stage_attn<<<dim3(256, 16), 256, 0, stream>>>(x, att_w1, att_b1, s_glob, x_t);
    dc_k2a_softmax_bias<<<1, 64, 0, stream>>>(s_glob, att_w2, att_b2, b_bank, pi, b_agg);
    dc_k2b_aggw<<<dim3(64, 16), 64, 0, stream>>>(w_bank, pi, A_frag);
    dc_k3_conv<<<4096, 256, 0, stream>>>(x_t, A_frag, b_agg, out);
}

// Round 6
// 202.865 us; speedup vs baseline: 1.4818x; 1.4818x over previous
//
#include <hip/hip_runtime.h>
#include <hip/hip_bf16.h>

typedef short short8 __attribute__((ext_vector_type(8)));
typedef float f32x4 __attribute__((ext_vector_type(4)));
typedef unsigned short ushort_t;

#define AS1 __attribute__((address_space(1)))
#define AS3 __attribute__((address_space(3)))

__device__ __forceinline__ ushort_t f2bf(float f) {
    unsigned u = __builtin_bit_cast(unsigned, f);
    unsigned r = (u + 0x7FFFu + ((u >> 16) & 1u)) >> 16;
    return (ushort_t)r;
}

__device__ __forceinline__ void gload_lds16(const void* g, void* l) {
    __builtin_amdgcn_global_load_lds((const AS1 unsigned*)g, (AS3 unsigned*)l, 16, 0, 0);
}

// -------------------------------------------------------------------------
// K0: zero the top/bottom padded border rows of x_t [16][258][258][64]
// -------------------------------------------------------------------------
__global__ __launch_bounds__(256) void dc_k0_zeroborder(ushort_t* __restrict__ x_t)
{
    const int b = blockIdx.x, t = threadIdx.x;
    const int n = b >> 1, row = (b & 1) ? 257 : 0;
    short8 z = {0, 0, 0, 0, 0, 0, 0, 0};
    short8* p = reinterpret_cast<short8*>(x_t + (size_t)(n * 258 + row) * 258 * 64);
    for (int i = t; i < 2064; i += 256) p[i] = z;  // 258*64/8
}

// -------------------------------------------------------------------------
// K1: per (n, row h): stage x[n][:, h, :] as bf16 [256px][64c] in LDS
// (XOR-swizzled), (a) write padded-NHWC bf16 x_t (+ zero col borders),
// (b) attention dot via MFMA: s[n][d] += sum_px relu(w1[d,:]·x[:,px]+b1[d])
// -------------------------------------------------------------------------
__global__ __launch_bounds__(256) void dc_k1_stage_attn(
    const float* __restrict__ x, const float* __restrict__ w1,
    const float* __restrict__ b1, float* __restrict__ s_glob,
    ushort_t* __restrict__ x_t)
{
    __shared__ unsigned xt32[256 * 32];   // 256 px * 64c bf16, swizzled
    __shared__ ushort_t w1s[16 * 64];
    __shared__ float sacc[16];

    const int n = blockIdx.y, h = blockIdx.x, t = threadIdx.x;
    if (t < 16) sacc[t] = 0.f;
#pragma unroll
    for (int q = 0; q < 4; ++q) { int idx = q * 256 + t; w1s[idx] = f2bf(w1[idx]); }

    const float* xr = x + ((size_t)n * 64) * 65536 + (size_t)h * 256;
    const int sw = (t & 7) << 2;
    for (int cp = 0; cp < 32; ++cp) {
        float a = xr[(size_t)(2 * cp) * 65536 + t];
        float b = xr[(size_t)(2 * cp + 1) * 65536 + t];
        xt32[(t * 32 + cp) ^ sw] = (unsigned)f2bf(a) | ((unsigned)f2bf(b) << 16);
    }
    __syncthreads();

    const int lane = t & 63, wv = t >> 6, l15 = lane & 15, lg = lane >> 4;
    const short8* xt8 = reinterpret_cast<const short8*>(xt32);
    const short8* w18 = reinterpret_cast<const short8*>(w1s);

    short8 a0 = w18[l15 * 8 + lg];
    short8 a1 = w18[l15 * 8 + 4 + lg];
    float b1v[4];
#pragma unroll
    for (int r = 0; r < 4; ++r) b1v[r] = b1[lg * 4 + r];

    float rs[4] = {0.f, 0.f, 0.f, 0.f};
#pragma unroll
    for (int q = 0; q < 4; ++q) {
        int px = (wv * 4 + q) * 16 + l15;
        int pb = px * 8, ps = px & 7;
        short8 bb0 = xt8[pb + (lg ^ ps)];
        short8 bb1 = xt8[pb + ((4 + lg) ^ ps)];
        f32x4 hacc = {0.f, 0.f, 0.f, 0.f};
        hacc = __builtin_amdgcn_mfma_f32_16x16x32_bf16(a0, bb0, hacc, 0, 0, 0);
        hacc = __builtin_amdgcn_mfma_f32_16x16x32_bf16(a1, bb1, hacc, 0, 0, 0);
#pragma unroll
        for (int r = 0; r < 4; ++r) rs[r] += fmaxf(hacc[r] + b1v[r], 0.f);
    }
#pragma unroll
    for (int off = 1; off < 16; off <<= 1)
#pragma unroll
        for (int r = 0; r < 4; ++r) rs[r] += __shfl_xor(rs[r], off);
    if (l15 == 0) {
#pragma unroll
        for (int r = 0; r < 4; ++r) atomicAdd(&sacc[lg * 4 + r], rs[r]);
    }
    __syncthreads();
    if (t < 16) atomicAdd(&s_glob[n * 16 + t], sacc[t]);

    // write-out padded NHWC bf16 (interior cols 1..256 of padded row h+1)
    ushort_t* xo = x_t + (((size_t)n * 258 + h + 1) * 258 + 1) * 64;
    const int cb = t & 7, pxr = t >> 3;
#pragma unroll
    for (int rr = 0; rr < 8; ++rr) {
        int px = rr * 32 + pxr;
        short8 v = xt8[px * 8 + (cb ^ (px & 7))];
        *reinterpret_cast<short8*>(xo + (size_t)px * 64 + cb * 8) = v;
    }
    // zero the left/right padded columns of this row
    if (t < 16) {
        short8 z = {0, 0, 0, 0, 0, 0, 0, 0};
        size_t colbase = (((size_t)n * 258 + h + 1) * 258 + ((t < 8) ? 0 : 257)) * 64;
        reinterpret_cast<short8*>(x_t + colbase)[t & 7] = z;
    }
}

// -------------------------------------------------------------------------
// K2a: s -> pooled -> softmax(pi) ; aggregate bias b_agg[n][o]
// -------------------------------------------------------------------------
__global__ void dc_k2a_softmax_bias(
    const float* __restrict__ s_glob, const float* __restrict__ w2,
    const float* __restrict__ b2, const float* __restrict__ b_bank,
    float* __restrict__ pi, float* __restrict__ b_agg)
{
    __shared__ float piL[16][4];
    const int t = threadIdx.x;
    if (t < 16) {
        int n = t;
        float z[4];
#pragma unroll
        for (int e = 0; e < 4; ++e) {
            float p = 0.f;
            for (int d = 0; d < 16; ++d) p += w2[e * 16 + d] * s_glob[n * 16 + d];
            z[e] = (b2[e] + p * (1.f / 65536.f)) * (1.f / 30.f);
        }
        float m = fmaxf(fmaxf(z[0], z[1]), fmaxf(z[2], z[3]));
        float ex[4], sum = 0.f;
#pragma unroll
        for (int e = 0; e < 4; ++e) { ex[e] = expf(z[e] - m); sum += ex[e]; }
        float inv = 1.f / sum;
#pragma unroll
        for (int e = 0; e < 4; ++e) { float v = ex[e] * inv; pi[n * 4 + e] = v; piL[n][e] = v; }
    }
    __syncthreads();
    for (int r = 0; r < 16; ++r) {
        float v = 0.f;
#pragma unroll
        for (int kw = 0; kw < 4; ++kw) v += piL[r][kw] * b_bank[t * 4 + kw];
        b_agg[r * 64 + t] = v;
    }
}

// -------------------------------------------------------------------------
// K2b: aggregate weights -> fragment-major A_frag[n][ks][mf][lane][8]
// ks = (ki*3+kj)*2+cc
// -------------------------------------------------------------------------
__global__ void dc_k2b_aggw(const float* __restrict__ w_bank,
                            const float* __restrict__ pi,
                            ushort_t* __restrict__ A_frag)
{
    __shared__ float lw[2304];  // one o-row: [4 kw][64 c][9 ij]
    const int o = blockIdx.x, n = blockIdx.y, t = threadIdx.x;  // 64 threads
    const float* wrow = w_bank + (size_t)o * 2304;
    for (int rr = 0; rr < 36; ++rr) lw[rr * 64 + t] = wrow[rr * 64 + t];
    float p0 = pi[n * 4 + 0], p1 = pi[n * 4 + 1], p2 = pi[n * 4 + 2], p3 = pi[n * 4 + 3];
    __syncthreads();
    const int c = t;
    const int cc = c >> 5, lg = (c >> 3) & 3, e = c & 7;
    const int mf = o >> 4, l15 = o & 15;
    ushort_t* base = A_frag + (size_t)n * 18 * 4 * 64 * 8;
#pragma unroll
    for (int ij = 0; ij < 9; ++ij) {
        float v = p0 * lw[0 * 576 + c * 9 + ij] + p1 * lw[1 * 576 + c * 9 + ij]
                + p2 * lw[2 * 576 + c * 9 + ij] + p3 * lw[3 * 576 + c * 9 + ij];
        int ks = ij * 2 + cc;
        base[(((ks * 4 + mf) * 64) + (lg * 16 + l15)) * 8 + e] = f2bf(v);
    }
}

// -------------------------------------------------------------------------
// K3: persistent row-strip implicit-GEMM conv. 256 blocks = 1/CU.
// Block = (n, 128-px half, 32-row strip), 4 waves; wave = 64 Co x 32 px.
// LDS: A-fragments (73.7 KB, staged once) + rolling 4-slot input window
// (4 x 17408 B, XOR-swizzled). Per row: prefetch padded row h+3 (distance
// = one row-compute >> L3 latency), compute 18 K-steps, store, then
// counted s_waitcnt vmcnt(16) + raw s_barrier (stage loads are oldest ->
// drained; stores stay in flight).
// -------------------------------------------------------------------------
__global__ __launch_bounds__(256, 1) void dc_k3_conv(
    const ushort_t* __restrict__ x_t, const ushort_t* __restrict__ A_frag,
    const float* __restrict__ b_agg, float* __restrict__ out)
{
    __shared__ char lds[73728 + 4 * 17408];   // 143,360 B
    char* ldsA = lds;
    char* ldsW = lds + 73728;

    int bid = blockIdx.x;
    int nb = (bid & 7) * 32 + (bid >> 3);   // XCD-chunked swizzle (256%8==0)
    const int n = nb >> 4;
    const int half = nb & 1;
    const int strip = (nb >> 1) & 7;
    const int h0 = strip * 32;
    const int w0 = half << 7;

    const int t = threadIdx.x, lane = t & 63, wv = t >> 6;
    const int l15 = lane & 15, lg = lane >> 4;
    const int pxl = wv * 32;

    const char* srcb = (const char*)x_t;
    const char* Asrc = (const char*)A_frag + (size_t)n * 73728;

    // ---- prologue: stage A (72 KB, 18 chunks/wave) ----
    for (int q = 0; q < 18; ++q) {
        int j = wv * 18 + q;
        gload_lds16(Asrc + j * 1024 + lane * 16, ldsA + j * 1024);
    }
    // ---- prologue: stage padded rows h0..h0+2 -> slots 0..2 ----
    for (int r = 0; r < 3; ++r) {
        size_t rowoff = ((size_t)(n * 258 + h0 + r) * 258 + w0) * 128;
        for (int k = wv; k < 17; k += 4) {
            unsigned q = k * 1024 + lane * 16;
            unsigned so = q ^ (((q >> 7) & 7) << 4);
            gload_lds16(srcb + rowoff + so, ldsW + r * 17408 + k * 1024);
        }
    }
    asm volatile("s_waitcnt vmcnt(0)" ::: "memory");
    __builtin_amdgcn_s_barrier();
    __builtin_amdgcn_sched_barrier(0);

    // precomputed swizzled B offsets: [kj][cc][nf]
    int boff[3][2][2];
#pragma unroll
    for (int kj = 0; kj < 3; ++kj)
#pragma unroll
        for (int cc = 0; cc < 2; ++cc)
#pragma unroll
            for (int nf = 0; nf < 2; ++nf) {
                int colL = pxl + nf * 16 + l15 + kj;
                boff[kj][cc][nf] = (colL * 128 + cc * 64 + lg * 16)
                                   ^ ((colL & 7) << 4);
            }
    const int aoff = lane * 16;

    const float* bn = b_agg + n * 64;
    float bv[4][4];
#pragma unroll
    for (int mf = 0; mf < 4; ++mf)
#pragma unroll
        for (int r = 0; r < 4; ++r) bv[mf][r] = bn[mf * 16 + lg * 4 + r];

#pragma unroll 1
    for (int i = 0; i < 32; ++i) {
        // ---- prefetch padded row h0+i+3 into slot (i+3)&3 ----
        if (i <= 30) {
            size_t rowoff = ((size_t)(n * 258 + h0 + i + 3) * 258 + w0) * 128;
            char* dst = ldsW + ((i + 3) & 3) * 17408;
            for (int k = wv; k < 17; k += 4) {
                unsigned q = k * 1024 + lane * 16;
                unsigned so = q ^ (((q >> 7) & 7) << 4);
                gload_lds16(srcb + rowoff + so, dst + k * 1024);
            }
        }
        __builtin_amdgcn_sched_barrier(0);

        // ---- compute output row h0+i ----
        const char* sbs[3] = { ldsW + ((i) & 3) * 17408,
                               ldsW + ((i + 1) & 3) * 17408,
                               ldsW + ((i + 2) & 3) * 17408 };
        f32x4 acc[4][2] = {};
        short8 afb[2][4], bfb[2][2];
#pragma unroll
        for (int mf = 0; mf < 4; ++mf)
            afb[0][mf] = *reinterpret_cast<const short8*>(ldsA + mf * 1024 + aoff);
#pragma unroll
        for (int nf = 0; nf < 2; ++nf)
            bfb[0][nf] = *reinterpret_cast<const short8*>(sbs[0] + boff[0][0][nf]);

#pragma unroll
        for (int ks = 0; ks < 18; ++ks) {
            const int cur = ks & 1, nxt = cur ^ 1;
            if (ks < 17) {
                const int k1 = ks + 1;
                const int ki1 = k1 / 6, r1 = k1 % 6;
                const int kj1 = r1 >> 1, cc1 = r1 & 1;
#pragma unroll
                for (int mf = 0; mf < 4; ++mf)
                    afb[nxt][mf] = *reinterpret_cast<const short8*>(
                        ldsA + (k1 * 4 + mf) * 1024 + aoff);
#pragma unroll
                for (int nf = 0; nf < 2; ++nf)
                    bfb[nxt][nf] = *reinterpret_cast<const short8*>(
                        sbs[ki1] + boff[kj1][cc1][nf]);
            }
#pragma unroll
            for (int mf = 0; mf < 4; ++mf)
#pragma unroll
                for (int nf = 0; nf < 2; ++nf)
                    acc[mf][nf] = __builtin_amdgcn_mfma_f32_16x16x32_bf16(
                        afb[cur][mf], bfb[cur][nf], acc[mf][nf], 0, 0, 0);
        }

        // ---- store output row ----
        const int h = h0 + i;
#pragma unroll
        for (int mf = 0; mf < 4; ++mf)
#pragma unroll
            for (int nf = 0; nf < 2; ++nf) {
                const int col = w0 + pxl + nf * 16 + l15;
#pragma unroll
                for (int r = 0; r < 4; ++r)
                    out[((size_t)(n * 64 + mf * 16 + lg * 4 + r) << 16)
                        + (size_t)h * 256 + col] = acc[mf][nf][r] + bv[mf][r];
            }

        // drain stage loads (oldest), leave stores in flight
        asm volatile("s_waitcnt vmcnt(16)" ::: "memory");
        __builtin_amdgcn_s_barrier();
        __builtin_amdgcn_sched_barrier(0);
    }
}

// -------------------------------------------------------------------------
extern "C" void kernel_launch(void* const* d_in, const int* in_sizes, int n_in,
                              void* d_out, int out_size, void* d_ws, size_t ws_size,
                              hipStream_t stream) {
    const float* x      = (const float*)d_in[0];
    const float* w_bank = (const float*)d_in[1];
    const float* b_bank = (const float*)d_in[2];
    const float* att_w1 = (const float*)d_in[3];
    const float* att_b1 = (const float*)d_in[4];
    const float* att_w2 = (const float*)d_in[5];
    const float* att_b2 = (const float*)d_in[6];
    float* out = (float*)d_out;

    char* ws = (char*)d_ws;
    float*    s_glob = (float*)ws;                     // 1 KB
    float*    pi     = (float*)(ws + 1024);            // 256 B
    float*    b_agg  = (float*)(ws + 2048);            // 4 KB
    ushort_t* A_frag = (ushort_t*)(ws + 8192);         // 1.125 MB
    ushort_t* x_t    = (ushort_t*)(ws + (2ull << 20)); // padded NHWC bf16, ~136.3 MB

    hipMemsetAsync(s_glob, 0, 16 * 16 * sizeof(float), stream);

    dc_k0_zeroborder<<<32, 256, 0, stream>>>(x_t);
    dc_k1_stage_attn<<<dim3(256, 16), 256, 0, stream>>>(x, att_w1, att_b1, s_glob, x_t);
    dc_k2a_softmax_bias<<<1, 64, 0, stream>>>(s_glob, att_w2, att_b2, b_bank, pi, b_agg);
    dc_k2b_aggw<<<dim3(64, 16), 64, 0, stream>>>(w_bank, pi, A_frag);
    dc_k3_conv<<<256, 256, 0, stream>>>(x_t, A_frag, b_agg, out);
}

// Round 7
// 197.456 us; speedup vs baseline: 1.5224x; 1.0274x over previous
//
#include <hip/hip_runtime.h>
#include <hip/hip_bf16.h>

typedef short short8 __attribute__((ext_vector_type(8)));
typedef float f32x4 __attribute__((ext_vector_type(4)));
typedef unsigned short ushort_t;

#define AS1 __attribute__((address_space(1)))
#define AS3 __attribute__((address_space(3)))

__device__ __forceinline__ ushort_t f2bf(float f) {
    unsigned u = __builtin_bit_cast(unsigned, f);
    unsigned r = (u + 0x7FFFu + ((u >> 16) & 1u)) >> 16;
    return (ushort_t)r;
}

__device__ __forceinline__ void gload_lds16(const void* g, void* l) {
    __builtin_amdgcn_global_load_lds((const AS1 unsigned*)g, (AS3 unsigned*)l, 16, 0, 0);
}

// -------------------------------------------------------------------------
// K0: zero the top/bottom padded border rows of x_t [16][258][258][64]
// -------------------------------------------------------------------------
__global__ __launch_bounds__(256) void dc_k0_zeroborder(ushort_t* __restrict__ x_t)
{
    const int b = blockIdx.x, t = threadIdx.x;
    const int n = b >> 1, row = (b & 1) ? 257 : 0;
    short8 z = {0, 0, 0, 0, 0, 0, 0, 0};
    short8* p = reinterpret_cast<short8*>(x_t + (size_t)(n * 258 + row) * 258 * 64);
    for (int i = t; i < 2064; i += 256) p[i] = z;  // 258*64/8
}

// -------------------------------------------------------------------------
// K1: per (n, row h): stage x[n][:, h, :] as bf16 [256px][64c] in LDS
// (XOR-swizzled), (a) write padded-NHWC bf16 x_t (+ zero col borders),
// (b) attention dot via MFMA: s[n][d] += sum_px relu(w1[d,:]·x[:,px]+b1[d])
// -------------------------------------------------------------------------
__global__ __launch_bounds__(256) void dc_k1_stage_attn(
    const float* __restrict__ x, const float* __restrict__ w1,
    const float* __restrict__ b1, float* __restrict__ s_glob,
    ushort_t* __restrict__ x_t)
{
    __shared__ unsigned xt32[256 * 32];   // 256 px * 64c bf16, swizzled
    __shared__ ushort_t w1s[16 * 64];
    __shared__ float sacc[16];

    const int n = blockIdx.y, h = blockIdx.x, t = threadIdx.x;
    if (t < 16) sacc[t] = 0.f;
#pragma unroll
    for (int q = 0; q < 4; ++q) { int idx = q * 256 + t; w1s[idx] = f2bf(w1[idx]); }

    const float* xr = x + ((size_t)n * 64) * 65536 + (size_t)h * 256;
    const int sw = (t & 7) << 2;
    for (int cp = 0; cp < 32; ++cp) {
        float a = xr[(size_t)(2 * cp) * 65536 + t];
        float b = xr[(size_t)(2 * cp + 1) * 65536 + t];
        xt32[(t * 32 + cp) ^ sw] = (unsigned)f2bf(a) | ((unsigned)f2bf(b) << 16);
    }
    __syncthreads();

    const int lane = t & 63, wv = t >> 6, l15 = lane & 15, lg = lane >> 4;
    const short8* xt8 = reinterpret_cast<const short8*>(xt32);
    const short8* w18 = reinterpret_cast<const short8*>(w1s);

    short8 a0 = w18[l15 * 8 + lg];
    short8 a1 = w18[l15 * 8 + 4 + lg];
    float b1v[4];
#pragma unroll
    for (int r = 0; r < 4; ++r) b1v[r] = b1[lg * 4 + r];

    float rs[4] = {0.f, 0.f, 0.f, 0.f};
#pragma unroll
    for (int q = 0; q < 4; ++q) {
        int px = (wv * 4 + q) * 16 + l15;
        int pb = px * 8, ps = px & 7;
        short8 bb0 = xt8[pb + (lg ^ ps)];
        short8 bb1 = xt8[pb + ((4 + lg) ^ ps)];
        f32x4 hacc = {0.f, 0.f, 0.f, 0.f};
        hacc = __builtin_amdgcn_mfma_f32_16x16x32_bf16(a0, bb0, hacc, 0, 0, 0);
        hacc = __builtin_amdgcn_mfma_f32_16x16x32_bf16(a1, bb1, hacc, 0, 0, 0);
#pragma unroll
        for (int r = 0; r < 4; ++r) rs[r] += fmaxf(hacc[r] + b1v[r], 0.f);
    }
#pragma unroll
    for (int off = 1; off < 16; off <<= 1)
#pragma unroll
        for (int r = 0; r < 4; ++r) rs[r] += __shfl_xor(rs[r], off);
    if (l15 == 0) {
#pragma unroll
        for (int r = 0; r < 4; ++r) atomicAdd(&sacc[lg * 4 + r], rs[r]);
    }
    __syncthreads();
    if (t < 16) atomicAdd(&s_glob[n * 16 + t], sacc[t]);

    // write-out padded NHWC bf16 (interior cols 1..256 of padded row h+1)
    ushort_t* xo = x_t + (((size_t)n * 258 + h + 1) * 258 + 1) * 64;
    const int cb = t & 7, pxr = t >> 3;
#pragma unroll
    for (int rr = 0; rr < 8; ++rr) {
        int px = rr * 32 + pxr;
        short8 v = xt8[px * 8 + (cb ^ (px & 7))];
        *reinterpret_cast<short8*>(xo + (size_t)px * 64 + cb * 8) = v;
    }
    // zero the left/right padded columns of this row
    if (t < 16) {
        short8 z = {0, 0, 0, 0, 0, 0, 0, 0};
        size_t colbase = (((size_t)n * 258 + h + 1) * 258 + ((t < 8) ? 0 : 257)) * 64;
        reinterpret_cast<short8*>(x_t + colbase)[t & 7] = z;
    }
}

// -------------------------------------------------------------------------
// K2a: s -> pooled -> softmax(pi) ; aggregate bias b_agg[n][o]
// -------------------------------------------------------------------------
__global__ void dc_k2a_softmax_bias(
    const float* __restrict__ s_glob, const float* __restrict__ w2,
    const float* __restrict__ b2, const float* __restrict__ b_bank,
    float* __restrict__ pi, float* __restrict__ b_agg)
{
    __shared__ float piL[16][4];
    const int t = threadIdx.x;
    if (t < 16) {
        int n = t;
        float z[4];
#pragma unroll
        for (int e = 0; e < 4; ++e) {
            float p = 0.f;
            for (int d = 0; d < 16; ++d) p += w2[e * 16 + d] * s_glob[n * 16 + d];
            z[e] = (b2[e] + p * (1.f / 65536.f)) * (1.f / 30.f);
        }
        float m = fmaxf(fmaxf(z[0], z[1]), fmaxf(z[2], z[3]));
        float ex[4], sum = 0.f;
#pragma unroll
        for (int e = 0; e < 4; ++e) { ex[e] = expf(z[e] - m); sum += ex[e]; }
        float inv = 1.f / sum;
#pragma unroll
        for (int e = 0; e < 4; ++e) { float v = ex[e] * inv; pi[n * 4 + e] = v; piL[n][e] = v; }
    }
    __syncthreads();
    for (int r = 0; r < 16; ++r) {
        float v = 0.f;
#pragma unroll
        for (int kw = 0; kw < 4; ++kw) v += piL[r][kw] * b_bank[t * 4 + kw];
        b_agg[r * 64 + t] = v;
    }
}

// -------------------------------------------------------------------------
// K2b: aggregate weights -> fragment-major A_frag[n][ks][mf][lane][8]
// ks = (ki*3+kj)*2+cc
// -------------------------------------------------------------------------
__global__ void dc_k2b_aggw(const float* __restrict__ w_bank,
                            const float* __restrict__ pi,
                            ushort_t* __restrict__ A_frag)
{
    __shared__ float lw[2304];  // one o-row: [4 kw][64 c][9 ij]
    const int o = blockIdx.x, n = blockIdx.y, t = threadIdx.x;  // 64 threads
    const float* wrow = w_bank + (size_t)o * 2304;
    for (int rr = 0; rr < 36; ++rr) lw[rr * 64 + t] = wrow[rr * 64 + t];
    float p0 = pi[n * 4 + 0], p1 = pi[n * 4 + 1], p2 = pi[n * 4 + 2], p3 = pi[n * 4 + 3];
    __syncthreads();
    const int c = t;
    const int cc = c >> 5, lg = (c >> 3) & 3, e = c & 7;
    const int mf = o >> 4, l15 = o & 15;
    ushort_t* base = A_frag + (size_t)n * 18 * 4 * 64 * 8;
#pragma unroll
    for (int ij = 0; ij < 9; ++ij) {
        float v = p0 * lw[0 * 576 + c * 9 + ij] + p1 * lw[1 * 576 + c * 9 + ij]
                + p2 * lw[2 * 576 + c * 9 + ij] + p3 * lw[3 * 576 + c * 9 + ij];
        int ks = ij * 2 + cc;
        base[(((ks * 4 + mf) * 64) + (lg * 16 + l15)) * 8 + e] = f2bf(v);
    }
}

// -------------------------------------------------------------------------
// K3: persistent row-strip implicit-GEMM conv, 2 OUTPUT ROWS PER ITER.
// 256 blocks = 1/CU. Block = (n, 128-px half, 32-row strip), 4 waves;
// wave = 64 Co x 32 px x 2 rows. Per K-step: 4 A-reads + 4 B-reads feed
// 16 MFMAs (0.5 ds_read/MFMA vs 0.75 single-row).
// LDS: A (72 KB, staged once) + 5-slot rolling input ring (5 x 17408 B).
// Iter j (rows 2j,2j+1): prefetch row 2j+4 -> slot (2j+4)%5 at start;
// after ki=0 phase (row 2j retired) mid-barrier, prefetch row 2j+5 into
// slot (2j)%5. vmcnt(0) before stores (prefetches are >=12 steps old).
// -------------------------------------------------------------------------
__global__ __launch_bounds__(256, 1) void dc_k3_conv(
    const ushort_t* __restrict__ x_t, const ushort_t* __restrict__ A_frag,
    const float* __restrict__ b_agg, float* __restrict__ out)
{
    __shared__ char lds[73728 + 5 * 17408];   // 160,768 B (<= 160 KiB)
    char* ldsA = lds;
    char* ldsW = lds + 73728;

    int bid = blockIdx.x;
    int nb = (bid & 7) * 32 + (bid >> 3);   // XCD-chunked swizzle (256%8==0)
    const int n = nb >> 4;
    const int half = nb & 1;
    const int strip = (nb >> 1) & 7;
    const int h0 = strip * 32;
    const int w0 = half << 7;

    const int t = threadIdx.x, lane = t & 63, wv = t >> 6;
    const int l15 = lane & 15, lg = lane >> 4;
    const int pxl = wv * 32;

    const char* srcb = (const char*)x_t;
    const char* Asrc = (const char*)A_frag + (size_t)n * 73728;

    // stage one padded input row (rel. row rr) into ring slot
    auto stage_row = [&](int rr, int slot) {
        size_t rowoff = ((size_t)(n * 258 + h0 + rr) * 258 + w0) * 128;
        char* dst = ldsW + slot * 17408;
        for (int k = wv; k < 17; k += 4) {
            unsigned q = k * 1024 + lane * 16;
            unsigned so = q ^ (((q >> 7) & 7) << 4);
            gload_lds16(srcb + rowoff + so, dst + k * 1024);
        }
    };

    // ---- prologue: stage A (72 KB) + padded rows 0..3 -> slots 0..3 ----
    for (int q = 0; q < 18; ++q) {
        int j = wv * 18 + q;
        gload_lds16(Asrc + j * 1024 + lane * 16, ldsA + j * 1024);
    }
    for (int r = 0; r < 4; ++r) stage_row(r, r);
    asm volatile("s_waitcnt vmcnt(0)" ::: "memory");
    __builtin_amdgcn_s_barrier();
    __builtin_amdgcn_sched_barrier(0);

    // precomputed swizzled B offsets: [kj][cc][nf]
    int boff[3][2][2];
#pragma unroll
    for (int kj = 0; kj < 3; ++kj)
#pragma unroll
        for (int cc = 0; cc < 2; ++cc)
#pragma unroll
            for (int nf = 0; nf < 2; ++nf) {
                int colL = pxl + nf * 16 + l15 + kj;
                boff[kj][cc][nf] = (colL * 128 + cc * 64 + lg * 16)
                                   ^ ((colL & 7) << 4);
            }
    const int aoff = lane * 16;

    const float* bn = b_agg + n * 64;
    float bv[4][4];
#pragma unroll
    for (int mf = 0; mf < 4; ++mf)
#pragma unroll
        for (int r = 0; r < 4; ++r) bv[mf][r] = bn[mf * 16 + lg * 4 + r];

#pragma unroll 1
    for (int j = 0; j < 16; ++j) {
        const int r0 = 2 * j;           // first padded row used this iter
        const int r4 = r0 + 4, r5 = r0 + 5;

        // ---- prefetch row r4 into the free slot ----
        if (r4 <= 33) stage_row(r4, r4 % 5);
        __builtin_amdgcn_sched_barrier(0);

        // slot bases for padded rows r0..r0+3
        const char* sb[4] = { ldsW + (r0 % 5) * 17408,
                              ldsW + ((r0 + 1) % 5) * 17408,
                              ldsW + ((r0 + 2) % 5) * 17408,
                              ldsW + ((r0 + 3) % 5) * 17408 };

        f32x4 acc[4][2][2] = {};
        short8 afb[2][4], bfb[2][2][2];   // [buf][mf] / [buf][o][nf]

        // preload ks=0 (ki=0,kj=0,cc=0): A + B rows 0,1
#pragma unroll
        for (int mf = 0; mf < 4; ++mf)
            afb[0][mf] = *reinterpret_cast<const short8*>(ldsA + mf * 1024 + aoff);
#pragma unroll
        for (int o = 0; o < 2; ++o)
#pragma unroll
            for (int nf = 0; nf < 2; ++nf)
                bfb[0][o][nf] = *reinterpret_cast<const short8*>(sb[o] + boff[0][0][nf]);

#pragma unroll
        for (int ks = 0; ks < 18; ++ks) {
            if (ks == 6) {
                // row r0 fully consumed (ki=0 done) -> recycle its slot
                __builtin_amdgcn_s_barrier();
                if (r5 <= 33) stage_row(r5, r0 % 5);
                __builtin_amdgcn_sched_barrier(0);
            }
            const int cur = ks & 1, nxt = cur ^ 1;
            if (ks < 17) {
                const int k1 = ks + 1;
                const int ki1 = k1 / 6, rem = k1 % 6;
                const int kj1 = rem >> 1, cc1 = rem & 1;
#pragma unroll
                for (int mf = 0; mf < 4; ++mf)
                    afb[nxt][mf] = *reinterpret_cast<const short8*>(
                        ldsA + (k1 * 4 + mf) * 1024 + aoff);
#pragma unroll
                for (int o = 0; o < 2; ++o)
#pragma unroll
                    for (int nf = 0; nf < 2; ++nf)
                        bfb[nxt][o][nf] = *reinterpret_cast<const short8*>(
                            sb[ki1 + o] + boff[kj1][cc1][nf]);
            }
#pragma unroll
            for (int mf = 0; mf < 4; ++mf)
#pragma unroll
                for (int nf = 0; nf < 2; ++nf)
#pragma unroll
                    for (int o = 0; o < 2; ++o)
                        acc[mf][nf][o] = __builtin_amdgcn_mfma_f32_16x16x32_bf16(
                            afb[cur][mf], bfb[cur][o][nf], acc[mf][nf][o], 0, 0, 0);
        }

        // drain prefetches (issued >=12 steps ago -> ~free), then store
        asm volatile("s_waitcnt vmcnt(0)" ::: "memory");
        __builtin_amdgcn_sched_barrier(0);
#pragma unroll
        for (int o = 0; o < 2; ++o) {
            const int h = h0 + r0 + o;
#pragma unroll
            for (int mf = 0; mf < 4; ++mf)
#pragma unroll
                for (int nf = 0; nf < 2; ++nf) {
                    const int col = w0 + pxl + nf * 16 + l15;
#pragma unroll
                    for (int r = 0; r < 4; ++r)
                        out[((size_t)(n * 64 + mf * 16 + lg * 4 + r) << 16)
                            + (size_t)h * 256 + col] = acc[mf][nf][o][r] + bv[mf][r];
                }
        }
        __builtin_amdgcn_sched_barrier(0);
        __builtin_amdgcn_s_barrier();   // slots r4,r5 now valid for next iter
    }
}

// -------------------------------------------------------------------------
extern "C" void kernel_launch(void* const* d_in, const int* in_sizes, int n_in,
                              void* d_out, int out_size, void* d_ws, size_t ws_size,
                              hipStream_t stream) {
    const float* x      = (const float*)d_in[0];
    const float* w_bank = (const float*)d_in[1];
    const float* b_bank = (const float*)d_in[2];
    const float* att_w1 = (const float*)d_in[3];
    const float* att_b1 = (const float*)d_in[4];
    const float* att_w2 = (const float*)d_in[5];
    const float* att_b2 = (const float*)d_in[6];
    float* out = (float*)d_out;

    char* ws = (char*)d_ws;
    float*    s_glob = (float*)ws;                     // 1 KB
    float*    pi     = (float*)(ws + 1024);            // 256 B
    float*    b_agg  = (float*)(ws + 2048);            // 4 KB
    ushort_t* A_frag = (ushort_t*)(ws + 8192);         // 1.125 MB
    ushort_t* x_t    = (ushort_t*)(ws + (2ull << 20)); // padded NHWC bf16, ~136.3 MB

    hipMemsetAsync(s_glob, 0, 16 * 16 * sizeof(float), stream);

    dc_k0_zeroborder<<<32, 256, 0, stream>>>(x_t);
    dc_k1_stage_attn<<<dim3(256, 16), 256, 0, stream>>>(x, att_w1, att_b1, s_glob, x_t);
    dc_k2a_softmax_bias<<<1, 64, 0, stream>>>(s_glob, att_w2, att_b2, b_bank, pi, b_agg);
    dc_k2b_aggw<<<dim3(64, 16), 64, 0, stream>>>(w_bank, pi, A_frag);
    dc_k3_conv<<<256, 256, 0, stream>>>(x_t, A_frag, b_agg, out);
}

// Round 8
// 195.599 us; speedup vs baseline: 1.5368x; 1.0095x over previous
//
#include <hip/hip_runtime.h>
#include <hip/hip_bf16.h>

typedef short short8 __attribute__((ext_vector_type(8)));
typedef float f32x4 __attribute__((ext_vector_type(4)));
typedef unsigned short ushort_t;

#define AS1 __attribute__((address_space(1)))
#define AS3 __attribute__((address_space(3)))

__device__ __forceinline__ ushort_t f2bf(float f) {
    unsigned u = __builtin_bit_cast(unsigned, f);
    unsigned r = (u + 0x7FFFu + ((u >> 16) & 1u)) >> 16;
    return (ushort_t)r;
}

__device__ __forceinline__ void gload_lds16(const void* g, void* l) {
    __builtin_amdgcn_global_load_lds((const AS1 unsigned*)g, (AS3 unsigned*)l, 16, 0, 0);
}

// -------------------------------------------------------------------------
// K0: zero the top/bottom padded border rows of x_t [16][258][258][64]
// -------------------------------------------------------------------------
__global__ __launch_bounds__(256) void dc_k0_zeroborder(ushort_t* __restrict__ x_t)
{
    const int b = blockIdx.x, t = threadIdx.x;
    const int n = b >> 1, row = (b & 1) ? 257 : 0;
    short8 z = {0, 0, 0, 0, 0, 0, 0, 0};
    short8* p = reinterpret_cast<short8*>(x_t + (size_t)(n * 258 + row) * 258 * 64);
    for (int i = t; i < 2064; i += 256) p[i] = z;  // 258*64/8
}

// -------------------------------------------------------------------------
// K1: per (n, row h): stage x[n][:, h, :] as bf16 [256px][64c] in LDS
// (XOR-swizzled), (a) write padded-NHWC bf16 x_t (+ zero col borders),
// (b) attention dot via MFMA: s[n][d] += sum_px relu(w1[d,:]·x[:,px]+b1[d])
// -------------------------------------------------------------------------
__global__ __launch_bounds__(256) void dc_k1_stage_attn(
    const float* __restrict__ x, const float* __restrict__ w1,
    const float* __restrict__ b1, float* __restrict__ s_glob,
    ushort_t* __restrict__ x_t)
{
    __shared__ unsigned xt32[256 * 32];   // 256 px * 64c bf16, swizzled
    __shared__ ushort_t w1s[16 * 64];
    __shared__ float sacc[16];

    const int n = blockIdx.y, h = blockIdx.x, t = threadIdx.x;
    if (t < 16) sacc[t] = 0.f;
#pragma unroll
    for (int q = 0; q < 4; ++q) { int idx = q * 256 + t; w1s[idx] = f2bf(w1[idx]); }

    const float* xr = x + ((size_t)n * 64) * 65536 + (size_t)h * 256;
    const int sw = (t & 7) << 2;
    for (int cp = 0; cp < 32; ++cp) {
        float a = xr[(size_t)(2 * cp) * 65536 + t];
        float b = xr[(size_t)(2 * cp + 1) * 65536 + t];
        xt32[(t * 32 + cp) ^ sw] = (unsigned)f2bf(a) | ((unsigned)f2bf(b) << 16);
    }
    __syncthreads();

    const int lane = t & 63, wv = t >> 6, l15 = lane & 15, lg = lane >> 4;
    const short8* xt8 = reinterpret_cast<const short8*>(xt32);
    const short8* w18 = reinterpret_cast<const short8*>(w1s);

    short8 a0 = w18[l15 * 8 + lg];
    short8 a1 = w18[l15 * 8 + 4 + lg];
    float b1v[4];
#pragma unroll
    for (int r = 0; r < 4; ++r) b1v[r] = b1[lg * 4 + r];

    float rs[4] = {0.f, 0.f, 0.f, 0.f};
#pragma unroll
    for (int q = 0; q < 4; ++q) {
        int px = (wv * 4 + q) * 16 + l15;
        int pb = px * 8, ps = px & 7;
        short8 bb0 = xt8[pb + (lg ^ ps)];
        short8 bb1 = xt8[pb + ((4 + lg) ^ ps)];
        f32x4 hacc = {0.f, 0.f, 0.f, 0.f};
        hacc = __builtin_amdgcn_mfma_f32_16x16x32_bf16(a0, bb0, hacc, 0, 0, 0);
        hacc = __builtin_amdgcn_mfma_f32_16x16x32_bf16(a1, bb1, hacc, 0, 0, 0);
#pragma unroll
        for (int r = 0; r < 4; ++r) rs[r] += fmaxf(hacc[r] + b1v[r], 0.f);
    }
#pragma unroll
    for (int off = 1; off < 16; off <<= 1)
#pragma unroll
        for (int r = 0; r < 4; ++r) rs[r] += __shfl_xor(rs[r], off);
    if (l15 == 0) {
#pragma unroll
        for (int r = 0; r < 4; ++r) atomicAdd(&sacc[lg * 4 + r], rs[r]);
    }
    __syncthreads();
    if (t < 16) atomicAdd(&s_glob[n * 16 + t], sacc[t]);

    // write-out padded NHWC bf16 (interior cols 1..256 of padded row h+1)
    ushort_t* xo = x_t + (((size_t)n * 258 + h + 1) * 258 + 1) * 64;
    const int cb = t & 7, pxr = t >> 3;
#pragma unroll
    for (int rr = 0; rr < 8; ++rr) {
        int px = rr * 32 + pxr;
        short8 v = xt8[px * 8 + (cb ^ (px & 7))];
        *reinterpret_cast<short8*>(xo + (size_t)px * 64 + cb * 8) = v;
    }
    // zero the left/right padded columns of this row
    if (t < 16) {
        short8 z = {0, 0, 0, 0, 0, 0, 0, 0};
        size_t colbase = (((size_t)n * 258 + h + 1) * 258 + ((t < 8) ? 0 : 257)) * 64;
        reinterpret_cast<short8*>(x_t + colbase)[t & 7] = z;
    }
}

// -------------------------------------------------------------------------
// K2a: s -> pooled -> softmax(pi) ; aggregate bias b_agg[n][o]
// -------------------------------------------------------------------------
__global__ void dc_k2a_softmax_bias(
    const float* __restrict__ s_glob, const float* __restrict__ w2,
    const float* __restrict__ b2, const float* __restrict__ b_bank,
    float* __restrict__ pi, float* __restrict__ b_agg)
{
    __shared__ float piL[16][4];
    const int t = threadIdx.x;
    if (t < 16) {
        int n = t;
        float z[4];
#pragma unroll
        for (int e = 0; e < 4; ++e) {
            float p = 0.f;
            for (int d = 0; d < 16; ++d) p += w2[e * 16 + d] * s_glob[n * 16 + d];
            z[e] = (b2[e] + p * (1.f / 65536.f)) * (1.f / 30.f);
        }
        float m = fmaxf(fmaxf(z[0], z[1]), fmaxf(z[2], z[3]));
        float ex[4], sum = 0.f;
#pragma unroll
        for (int e = 0; e < 4; ++e) { ex[e] = expf(z[e] - m); sum += ex[e]; }
        float inv = 1.f / sum;
#pragma unroll
        for (int e = 0; e < 4; ++e) { float v = ex[e] * inv; pi[n * 4 + e] = v; piL[n][e] = v; }
    }
    __syncthreads();
    for (int r = 0; r < 16; ++r) {
        float v = 0.f;
#pragma unroll
        for (int kw = 0; kw < 4; ++kw) v += piL[r][kw] * b_bank[t * 4 + kw];
        b_agg[r * 64 + t] = v;
    }
}

// -------------------------------------------------------------------------
// K2b: aggregate weights -> fragment-major A_frag[n][ks][mf][lane][8]
// ks = (ki*3+kj)*2+cc
// -------------------------------------------------------------------------
__global__ void dc_k2b_aggw(const float* __restrict__ w_bank,
                            const float* __restrict__ pi,
                            ushort_t* __restrict__ A_frag)
{
    __shared__ float lw[2304];  // one o-row: [4 kw][64 c][9 ij]
    const int o = blockIdx.x, n = blockIdx.y, t = threadIdx.x;  // 64 threads
    const float* wrow = w_bank + (size_t)o * 2304;
    for (int rr = 0; rr < 36; ++rr) lw[rr * 64 + t] = wrow[rr * 64 + t];
    float p0 = pi[n * 4 + 0], p1 = pi[n * 4 + 1], p2 = pi[n * 4 + 2], p3 = pi[n * 4 + 3];
    __syncthreads();
    const int c = t;
    const int cc = c >> 5, lg = (c >> 3) & 3, e = c & 7;
    const int mf = o >> 4, l15 = o & 15;
    ushort_t* base = A_frag + (size_t)n * 18 * 4 * 64 * 8;
#pragma unroll
    for (int ij = 0; ij < 9; ++ij) {
        float v = p0 * lw[0 * 576 + c * 9 + ij] + p1 * lw[1 * 576 + c * 9 + ij]
                + p2 * lw[2 * 576 + c * 9 + ij] + p3 * lw[3 * 576 + c * 9 + ij];
        int ks = ij * 2 + cc;
        base[(((ks * 4 + mf) * 64) + (lg * 16 + l15)) * 8 + e] = f2bf(v);
    }
}

// -------------------------------------------------------------------------
// K3: persistent row-strip implicit-GEMM conv, 2 output rows per iter.
// 256 blocks = 1/CU. Per iter VMEM order: [prefetch loads (10/wave)] ...
// [64 dword stores/wave] -> s_waitcnt vmcnt(63) guarantees the loads
// retired (FIFO) while leaving this iter's stores in flight -> store
// drain overlaps next iter's compute (was the 2x serialization).
// LDS: A (72 KB, staged once) + 5-slot rolling input ring (5 x 17408 B).
// -------------------------------------------------------------------------
__global__ __launch_bounds__(256, 1) void dc_k3_conv(
    const ushort_t* __restrict__ x_t, const ushort_t* __restrict__ A_frag,
    const float* __restrict__ b_agg, float* __restrict__ out)
{
    __shared__ char lds[73728 + 5 * 17408];   // 160,768 B (<= 160 KiB)
    char* ldsA = lds;
    char* ldsW = lds + 73728;

    int bid = blockIdx.x;
    int nb = (bid & 7) * 32 + (bid >> 3);   // XCD-chunked swizzle (256%8==0)
    const int n = nb >> 4;
    const int half = nb & 1;
    const int strip = (nb >> 1) & 7;
    const int h0 = strip * 32;
    const int w0 = half << 7;

    const int t = threadIdx.x, lane = t & 63, wv = t >> 6;
    const int l15 = lane & 15, lg = lane >> 4;
    const int pxl = wv * 32;

    const char* srcb = (const char*)x_t;
    const char* Asrc = (const char*)A_frag + (size_t)n * 73728;

    // stage one padded input row (rel. row rr) into ring slot
    auto stage_row = [&](int rr, int slot) {
        size_t rowoff = ((size_t)(n * 258 + h0 + rr) * 258 + w0) * 128;
        char* dst = ldsW + slot * 17408;
        for (int k = wv; k < 17; k += 4) {
            unsigned q = k * 1024 + lane * 16;
            unsigned so = q ^ (((q >> 7) & 7) << 4);
            gload_lds16(srcb + rowoff + so, dst + k * 1024);
        }
    };

    // ---- prologue: stage A (72 KB) + padded rows 0..3 -> slots 0..3 ----
    for (int q = 0; q < 18; ++q) {
        int j = wv * 18 + q;
        gload_lds16(Asrc + j * 1024 + lane * 16, ldsA + j * 1024);
    }
    for (int r = 0; r < 4; ++r) stage_row(r, r);
    asm volatile("s_waitcnt vmcnt(0)" ::: "memory");
    __builtin_amdgcn_s_barrier();
    __builtin_amdgcn_sched_barrier(0);

    // precomputed swizzled B offsets: [kj][cc][nf]
    int boff[3][2][2];
#pragma unroll
    for (int kj = 0; kj < 3; ++kj)
#pragma unroll
        for (int cc = 0; cc < 2; ++cc)
#pragma unroll
            for (int nf = 0; nf < 2; ++nf) {
                int colL = pxl + nf * 16 + l15 + kj;
                boff[kj][cc][nf] = (colL * 128 + cc * 64 + lg * 16)
                                   ^ ((colL & 7) << 4);
            }
    const int aoff = lane * 16;

    const float* bn = b_agg + n * 64;
    float bv[4][4];
#pragma unroll
    for (int mf = 0; mf < 4; ++mf)
#pragma unroll
        for (int r = 0; r < 4; ++r) bv[mf][r] = bn[mf * 16 + lg * 4 + r];

#pragma unroll 1
    for (int j = 0; j < 16; ++j) {
        const int r0 = 2 * j;           // first padded row used this iter
        const int r4 = r0 + 4, r5 = r0 + 5;

        // ---- prefetch row r4 into the free slot (loads BEFORE stores) ----
        if (r4 <= 33) stage_row(r4, r4 % 5);
        __builtin_amdgcn_sched_barrier(0);

        // slot bases for padded rows r0..r0+3
        const char* sb[4] = { ldsW + (r0 % 5) * 17408,
                              ldsW + ((r0 + 1) % 5) * 17408,
                              ldsW + ((r0 + 2) % 5) * 17408,
                              ldsW + ((r0 + 3) % 5) * 17408 };

        f32x4 acc[4][2][2] = {};
        short8 afb[2][4], bfb[2][2][2];   // [buf][mf] / [buf][o][nf]

        // preload ks=0 (ki=0,kj=0,cc=0): A + B rows 0,1
#pragma unroll
        for (int mf = 0; mf < 4; ++mf)
            afb[0][mf] = *reinterpret_cast<const short8*>(ldsA + mf * 1024 + aoff);
#pragma unroll
        for (int o = 0; o < 2; ++o)
#pragma unroll
            for (int nf = 0; nf < 2; ++nf)
                bfb[0][o][nf] = *reinterpret_cast<const short8*>(sb[o] + boff[0][0][nf]);

#pragma unroll
        for (int ks = 0; ks < 18; ++ks) {
            if (ks == 6) {
                // row r0 fully consumed (ki=0 done) -> recycle its slot
                __builtin_amdgcn_s_barrier();
                if (r5 <= 33) stage_row(r5, r0 % 5);
                __builtin_amdgcn_sched_barrier(0);
            }
            const int cur = ks & 1, nxt = cur ^ 1;
            if (ks < 17) {
                const int k1 = ks + 1;
                const int ki1 = k1 / 6, rem = k1 % 6;
                const int kj1 = rem >> 1, cc1 = rem & 1;
#pragma unroll
                for (int mf = 0; mf < 4; ++mf)
                    afb[nxt][mf] = *reinterpret_cast<const short8*>(
                        ldsA + (k1 * 4 + mf) * 1024 + aoff);
#pragma unroll
                for (int o = 0; o < 2; ++o)
#pragma unroll
                    for (int nf = 0; nf < 2; ++nf)
                        bfb[nxt][o][nf] = *reinterpret_cast<const short8*>(
                            sb[ki1 + o] + boff[kj1][cc1][nf]);
            }
#pragma unroll
            for (int mf = 0; mf < 4; ++mf)
#pragma unroll
                for (int nf = 0; nf < 2; ++nf)
#pragma unroll
                    for (int o = 0; o < 2; ++o)
                        acc[mf][nf][o] = __builtin_amdgcn_mfma_f32_16x16x32_bf16(
                            afb[cur][mf], bfb[cur][o][nf], acc[mf][nf][o], 0, 0, 0);
        }

        // ---- stores (no wait: VMEM FIFO puts them behind this iter's loads)
#pragma unroll
        for (int o = 0; o < 2; ++o) {
            const int h = h0 + r0 + o;
#pragma unroll
            for (int mf = 0; mf < 4; ++mf)
#pragma unroll
                for (int nf = 0; nf < 2; ++nf) {
                    const int col = w0 + pxl + nf * 16 + l15;
#pragma unroll
                    for (int r = 0; r < 4; ++r)
                        out[((size_t)(n * 64 + mf * 16 + lg * 4 + r) << 16)
                            + (size_t)h * 256 + col] = acc[mf][nf][o][r] + bv[mf][r];
                }
        }
        __builtin_amdgcn_sched_barrier(0);
        // wait until <=63 VMEM ops outstanding: the 10 prefetch loads (oldest)
        // are guaranteed retired; up to 63 of this iter's 64 stores may
        // remain in flight and drain under next iter's compute.
        asm volatile("s_waitcnt vmcnt(63)" ::: "memory");
        __builtin_amdgcn_s_barrier();   // slots r4,r5 now valid for next iter
        __builtin_amdgcn_sched_barrier(0);
    }
}

// -------------------------------------------------------------------------
extern "C" void kernel_launch(void* const* d_in, const int* in_sizes, int n_in,
                              void* d_out, int out_size, void* d_ws, size_t ws_size,
                              hipStream_t stream) {
    const float* x      = (const float*)d_in[0];
    const float* w_bank = (const float*)d_in[1];
    const float* b_bank = (const float*)d_in[2];
    const float* att_w1 = (const float*)d_in[3];
    const float* att_b1 = (const float*)d_in[4];
    const float* att_w2 = (const float*)d_in[5];
    const float* att_b2 = (const float*)d_in[6];
    float* out = (float*)d_out;

    char* ws = (char*)d_ws;
    float*    s_glob = (float*)ws;                     // 1 KB
    float*    pi     = (float*)(ws + 1024);            // 256 B
    float*    b_agg  = (float*)(ws + 2048);            // 4 KB
    ushort_t* A_frag = (ushort_t*)(ws + 8192);         // 1.125 MB
    ushort_t* x_t    = (ushort_t*)(ws + (2ull << 20)); // padded NHWC bf16, ~136.3 MB

    hipMemsetAsync(s_glob, 0, 16 * 16 * sizeof(float), stream);

    dc_k0_zeroborder<<<32, 256, 0, stream>>>(x_t);
    dc_k1_stage_attn<<<dim3(256, 16), 256, 0, stream>>>(x, att_w1, att_b1, s_glob, x_t);
    dc_k2a_softmax_bias<<<1, 64, 0, stream>>>(s_glob, att_w2, att_b2, b_bank, pi, b_agg);
    dc_k2b_aggw<<<dim3(64, 16), 64, 0, stream>>>(w_bank, pi, A_frag);
    dc_k3_conv<<<256, 256, 0, stream>>>(x_t, A_frag, b_agg, out);
}

// Round 9
// 190.875 us; speedup vs baseline: 1.5749x; 1.0247x over previous
//
#include <hip/hip_runtime.h>
#include <hip/hip_bf16.h>

typedef short short8 __attribute__((ext_vector_type(8)));
typedef float f32x4 __attribute__((ext_vector_type(4)));
typedef unsigned short ushort_t;

#define AS1 __attribute__((address_space(1)))
#define AS3 __attribute__((address_space(3)))

__device__ __forceinline__ ushort_t f2bf(float f) {
    unsigned u = __builtin_bit_cast(unsigned, f);
    unsigned r = (u + 0x7FFFu + ((u >> 16) & 1u)) >> 16;
    return (ushort_t)r;
}

__device__ __forceinline__ void gload_lds16(const void* g, void* l) {
    __builtin_amdgcn_global_load_lds((const AS1 unsigned*)g, (AS3 unsigned*)l, 16, 0, 0);
}

// -------------------------------------------------------------------------
// K0: zero the top/bottom padded border rows of x_t [16][258][258][64]
// -------------------------------------------------------------------------
__global__ __launch_bounds__(256) void dc_k0_zeroborder(ushort_t* __restrict__ x_t)
{
    const int b = blockIdx.x, t = threadIdx.x;
    const int n = b >> 1, row = (b & 1) ? 257 : 0;
    short8 z = {0, 0, 0, 0, 0, 0, 0, 0};
    short8* p = reinterpret_cast<short8*>(x_t + (size_t)(n * 258 + row) * 258 * 64);
    for (int i = t; i < 2064; i += 256) p[i] = z;  // 258*64/8
}

// -------------------------------------------------------------------------
// K1: per (n, row h): stage x[n][:, h, :] as bf16 [256px][64c] in LDS
// (XOR-swizzled), (a) write padded-NHWC bf16 x_t (+ zero col borders),
// (b) attention dot via MFMA: s[n][d] += sum_px relu(w1[d,:]·x[:,px]+b1[d])
// -------------------------------------------------------------------------
__global__ __launch_bounds__(256) void dc_k1_stage_attn(
    const float* __restrict__ x, const float* __restrict__ w1,
    const float* __restrict__ b1, float* __restrict__ s_glob,
    ushort_t* __restrict__ x_t)
{
    __shared__ unsigned xt32[256 * 32];   // 256 px * 64c bf16, swizzled
    __shared__ ushort_t w1s[16 * 64];
    __shared__ float sacc[16];

    const int n = blockIdx.y, h = blockIdx.x, t = threadIdx.x;
    if (t < 16) sacc[t] = 0.f;
#pragma unroll
    for (int q = 0; q < 4; ++q) { int idx = q * 256 + t; w1s[idx] = f2bf(w1[idx]); }

    const float* xr = x + ((size_t)n * 64) * 65536 + (size_t)h * 256;
    const int sw = (t & 7) << 2;
    for (int cp = 0; cp < 32; ++cp) {
        float a = xr[(size_t)(2 * cp) * 65536 + t];
        float b = xr[(size_t)(2 * cp + 1) * 65536 + t];
        xt32[(t * 32 + cp) ^ sw] = (unsigned)f2bf(a) | ((unsigned)f2bf(b) << 16);
    }
    __syncthreads();

    const int lane = t & 63, wv = t >> 6, l15 = lane & 15, lg = lane >> 4;
    const short8* xt8 = reinterpret_cast<const short8*>(xt32);
    const short8* w18 = reinterpret_cast<const short8*>(w1s);

    short8 a0 = w18[l15 * 8 + lg];
    short8 a1 = w18[l15 * 8 + 4 + lg];
    float b1v[4];
#pragma unroll
    for (int r = 0; r < 4; ++r) b1v[r] = b1[lg * 4 + r];

    float rs[4] = {0.f, 0.f, 0.f, 0.f};
#pragma unroll
    for (int q = 0; q < 4; ++q) {
        int px = (wv * 4 + q) * 16 + l15;
        int pb = px * 8, ps = px & 7;
        short8 bb0 = xt8[pb + (lg ^ ps)];
        short8 bb1 = xt8[pb + ((4 + lg) ^ ps)];
        f32x4 hacc = {0.f, 0.f, 0.f, 0.f};
        hacc = __builtin_amdgcn_mfma_f32_16x16x32_bf16(a0, bb0, hacc, 0, 0, 0);
        hacc = __builtin_amdgcn_mfma_f32_16x16x32_bf16(a1, bb1, hacc, 0, 0, 0);
#pragma unroll
        for (int r = 0; r < 4; ++r) rs[r] += fmaxf(hacc[r] + b1v[r], 0.f);
    }
#pragma unroll
    for (int off = 1; off < 16; off <<= 1)
#pragma unroll
        for (int r = 0; r < 4; ++r) rs[r] += __shfl_xor(rs[r], off);
    if (l15 == 0) {
#pragma unroll
        for (int r = 0; r < 4; ++r) atomicAdd(&sacc[lg * 4 + r], rs[r]);
    }
    __syncthreads();
    if (t < 16) atomicAdd(&s_glob[n * 16 + t], sacc[t]);

    // write-out padded NHWC bf16 (interior cols 1..256 of padded row h+1)
    ushort_t* xo = x_t + (((size_t)n * 258 + h + 1) * 258 + 1) * 64;
    const int cb = t & 7, pxr = t >> 3;
#pragma unroll
    for (int rr = 0; rr < 8; ++rr) {
        int px = rr * 32 + pxr;
        short8 v = xt8[px * 8 + (cb ^ (px & 7))];
        *reinterpret_cast<short8*>(xo + (size_t)px * 64 + cb * 8) = v;
    }
    // zero the left/right padded columns of this row
    if (t < 16) {
        short8 z = {0, 0, 0, 0, 0, 0, 0, 0};
        size_t colbase = (((size_t)n * 258 + h + 1) * 258 + ((t < 8) ? 0 : 257)) * 64;
        reinterpret_cast<short8*>(x_t + colbase)[t & 7] = z;
    }
}

// -------------------------------------------------------------------------
// K2a: s -> pooled -> softmax(pi) ; aggregate bias b_agg[n][o]
// -------------------------------------------------------------------------
__global__ void dc_k2a_softmax_bias(
    const float* __restrict__ s_glob, const float* __restrict__ w2,
    const float* __restrict__ b2, const float* __restrict__ b_bank,
    float* __restrict__ pi, float* __restrict__ b_agg)
{
    __shared__ float piL[16][4];
    const int t = threadIdx.x;
    if (t < 16) {
        int n = t;
        float z[4];
#pragma unroll
        for (int e = 0; e < 4; ++e) {
            float p = 0.f;
            for (int d = 0; d < 16; ++d) p += w2[e * 16 + d] * s_glob[n * 16 + d];
            z[e] = (b2[e] + p * (1.f / 65536.f)) * (1.f / 30.f);
        }
        float m = fmaxf(fmaxf(z[0], z[1]), fmaxf(z[2], z[3]));
        float ex[4], sum = 0.f;
#pragma unroll
        for (int e = 0; e < 4; ++e) { ex[e] = expf(z[e] - m); sum += ex[e]; }
        float inv = 1.f / sum;
#pragma unroll
        for (int e = 0; e < 4; ++e) { float v = ex[e] * inv; pi[n * 4 + e] = v; piL[n][e] = v; }
    }
    __syncthreads();
    for (int r = 0; r < 16; ++r) {
        float v = 0.f;
#pragma unroll
        for (int kw = 0; kw < 4; ++kw) v += piL[r][kw] * b_bank[t * 4 + kw];
        b_agg[r * 64 + t] = v;
    }
}

// -------------------------------------------------------------------------
// K2b: aggregate weights -> fragment-major A_frag[n][ks][mf][lane][8]
// ks = (ki*3+kj)*2+cc
// -------------------------------------------------------------------------
__global__ void dc_k2b_aggw(const float* __restrict__ w_bank,
                            const float* __restrict__ pi,
                            ushort_t* __restrict__ A_frag)
{
    __shared__ float lw[2304];  // one o-row: [4 kw][64 c][9 ij]
    const int o = blockIdx.x, n = blockIdx.y, t = threadIdx.x;  // 64 threads
    const float* wrow = w_bank + (size_t)o * 2304;
    for (int rr = 0; rr < 36; ++rr) lw[rr * 64 + t] = wrow[rr * 64 + t];
    float p0 = pi[n * 4 + 0], p1 = pi[n * 4 + 1], p2 = pi[n * 4 + 2], p3 = pi[n * 4 + 3];
    __syncthreads();
    const int c = t;
    const int cc = c >> 5, lg = (c >> 3) & 3, e = c & 7;
    const int mf = o >> 4, l15 = o & 15;
    ushort_t* base = A_frag + (size_t)n * 18 * 4 * 64 * 8;
#pragma unroll
    for (int ij = 0; ij < 9; ++ij) {
        float v = p0 * lw[0 * 576 + c * 9 + ij] + p1 * lw[1 * 576 + c * 9 + ij]
                + p2 * lw[2 * 576 + c * 9 + ij] + p3 * lw[3 * 576 + c * 9 + ij];
        int ks = ij * 2 + cc;
        base[(((ks * 4 + mf) * 64) + (lg * 16 + l15)) * 8 + e] = f2bf(v);
    }
}

// -------------------------------------------------------------------------
// K3: persistent row-strip implicit-GEMM conv, 2 output rows per iter,
// 8 WAVES (512 threads) = 2 waves/SIMD for TLP (1 wave/SIMD cannot
// saturate the MFMA pipe and exposes every latency). Wave = 64 Co x 16 px
// x 2 rows: per K-step 4 A + 2 B ds_reads feed 8 MFMAs.
// 256 blocks = 1/CU. LDS: A (72 KB, staged once) + 5-slot rolling input
// ring (5 x 17408 B) = 160,768 B. setprio(1) around MFMA cluster (T5).
// Counted vmcnt(31) at iter end: stage loads (<=6/wave, oldest) retired,
// stores keep draining under next iter's compute.
// -------------------------------------------------------------------------
__global__ __launch_bounds__(512, 1) void dc_k3_conv(
    const ushort_t* __restrict__ x_t, const ushort_t* __restrict__ A_frag,
    const float* __restrict__ b_agg, float* __restrict__ out)
{
    __shared__ char lds[73728 + 5 * 17408];   // 160,768 B (<= 160 KiB)
    char* ldsA = lds;
    char* ldsW = lds + 73728;

    int bid = blockIdx.x;
    int nb = (bid & 7) * 32 + (bid >> 3);   // XCD-chunked swizzle (256%8==0)
    const int n = nb >> 4;
    const int half = nb & 1;
    const int strip = (nb >> 1) & 7;
    const int h0 = strip * 32;
    const int w0 = half << 7;

    const int t = threadIdx.x, lane = t & 63, wv = t >> 6;   // wv in 0..7
    const int l15 = lane & 15, lg = lane >> 4;
    const int pxl = wv * 16;                                  // 16-px slice

    const char* srcb = (const char*)x_t;
    const char* Asrc = (const char*)A_frag + (size_t)n * 73728;

    // stage one padded input row (rel. row rr) into ring slot (8-wave split)
    auto stage_row = [&](int rr, int slot) {
        size_t rowoff = ((size_t)(n * 258 + h0 + rr) * 258 + w0) * 128;
        char* dst = ldsW + slot * 17408;
        for (int k = wv; k < 17; k += 8) {
            unsigned q = k * 1024 + lane * 16;
            unsigned so = q ^ (((q >> 7) & 7) << 4);
            gload_lds16(srcb + rowoff + so, dst + k * 1024);
        }
    };

    // ---- prologue: stage A (72 KB, 9 chunks/wave) + rows 0..3 ----
    for (int q = 0; q < 9; ++q) {
        int j = wv * 9 + q;
        gload_lds16(Asrc + j * 1024 + lane * 16, ldsA + j * 1024);
    }
    for (int r = 0; r < 4; ++r) stage_row(r, r);
    asm volatile("s_waitcnt vmcnt(0)" ::: "memory");
    __builtin_amdgcn_s_barrier();
    __builtin_amdgcn_sched_barrier(0);

    // precomputed swizzled B offsets: [kj][cc]
    int boff[3][2];
#pragma unroll
    for (int kj = 0; kj < 3; ++kj)
#pragma unroll
        for (int cc = 0; cc < 2; ++cc) {
            int colL = pxl + l15 + kj;
            boff[kj][cc] = (colL * 128 + cc * 64 + lg * 16)
                           ^ ((colL & 7) << 4);
        }
    const int aoff = lane * 16;

    const float* bn = b_agg + n * 64;
    float bv[4][4];
#pragma unroll
    for (int mf = 0; mf < 4; ++mf)
#pragma unroll
        for (int r = 0; r < 4; ++r) bv[mf][r] = bn[mf * 16 + lg * 4 + r];

#pragma unroll 1
    for (int j = 0; j < 16; ++j) {
        const int r0 = 2 * j;           // first padded row used this iter
        const int r4 = r0 + 4, r5 = r0 + 5;

        // ---- prefetch row r4 into the free slot (loads BEFORE stores) ----
        if (r4 <= 33) stage_row(r4, r4 % 5);
        __builtin_amdgcn_sched_barrier(0);

        // slot bases for padded rows r0..r0+3
        const char* sb[4] = { ldsW + (r0 % 5) * 17408,
                              ldsW + ((r0 + 1) % 5) * 17408,
                              ldsW + ((r0 + 2) % 5) * 17408,
                              ldsW + ((r0 + 3) % 5) * 17408 };

        f32x4 acc[4][2] = {};             // [mf][o]
        short8 afb[2][4], bfb[2][2];      // [buf][mf] / [buf][o]

        // preload ks=0 (ki=0,kj=0,cc=0): A + B rows 0,1
#pragma unroll
        for (int mf = 0; mf < 4; ++mf)
            afb[0][mf] = *reinterpret_cast<const short8*>(ldsA + mf * 1024 + aoff);
#pragma unroll
        for (int o = 0; o < 2; ++o)
            bfb[0][o] = *reinterpret_cast<const short8*>(sb[o] + boff[0][0]);

#pragma unroll
        for (int ks = 0; ks < 18; ++ks) {
            if (ks == 6) {
                // row r0 fully consumed (ki=0 done) -> recycle its slot
                __builtin_amdgcn_s_barrier();
                if (r5 <= 33) stage_row(r5, r0 % 5);
                __builtin_amdgcn_sched_barrier(0);
            }
            const int cur = ks & 1, nxt = cur ^ 1;
            if (ks < 17) {
                const int k1 = ks + 1;
                const int ki1 = k1 / 6, rem = k1 % 6;
                const int kj1 = rem >> 1, cc1 = rem & 1;
#pragma unroll
                for (int mf = 0; mf < 4; ++mf)
                    afb[nxt][mf] = *reinterpret_cast<const short8*>(
                        ldsA + (k1 * 4 + mf) * 1024 + aoff);
#pragma unroll
                for (int o = 0; o < 2; ++o)
                    bfb[nxt][o] = *reinterpret_cast<const short8*>(
                        sb[ki1 + o] + boff[kj1][cc1]);
            }
            __builtin_amdgcn_s_setprio(1);
#pragma unroll
            for (int mf = 0; mf < 4; ++mf)
#pragma unroll
                for (int o = 0; o < 2; ++o)
                    acc[mf][o] = __builtin_amdgcn_mfma_f32_16x16x32_bf16(
                        afb[cur][mf], bfb[cur][o], acc[mf][o], 0, 0, 0);
            __builtin_amdgcn_s_setprio(0);
        }

        // ---- stores (behind this iter's loads in the VMEM FIFO) ----
#pragma unroll
        for (int o = 0; o < 2; ++o) {
            const int h = h0 + r0 + o;
#pragma unroll
            for (int mf = 0; mf < 4; ++mf) {
                const int col = w0 + pxl + l15;
#pragma unroll
                for (int r = 0; r < 4; ++r)
                    out[((size_t)(n * 64 + mf * 16 + lg * 4 + r) << 16)
                        + (size_t)h * 256 + col] = acc[mf][o][r] + bv[mf][r];
            }
        }
        __builtin_amdgcn_sched_barrier(0);
        // <=31 outstanding: >=7 retired (FIFO) covers the <=6 stage loads;
        // ~25 stores drain under next iter's compute.
        asm volatile("s_waitcnt vmcnt(31)" ::: "memory");
        __builtin_amdgcn_s_barrier();   // slots r4,r5 now valid for next iter
        __builtin_amdgcn_sched_barrier(0);
    }
}

// -------------------------------------------------------------------------
extern "C" void kernel_launch(void* const* d_in, const int* in_sizes, int n_in,
                              void* d_out, int out_size, void* d_ws, size_t ws_size,
                              hipStream_t stream) {
    const float* x      = (const float*)d_in[0];
    const float* w_bank = (const float*)d_in[1];
    const float* b_bank = (const float*)d_in[2];
    const float* att_w1 = (const float*)d_in[3];
    const float* att_b1 = (const float*)d_in[4];
    const float* att_w2 = (const float*)d_in[5];
    const float* att_b2 = (const float*)d_in[6];
    float* out = (float*)d_out;

    char* ws = (char*)d_ws;
    float*    s_glob = (float*)ws;                     // 1 KB
    float*    pi     = (float*)(ws + 1024);            // 256 B
    float*    b_agg  = (float*)(ws + 2048);            // 4 KB
    ushort_t* A_frag = (ushort_t*)(ws + 8192);         // 1.125 MB
    ushort_t* x_t    = (ushort_t*)(ws + (2ull << 20)); // padded NHWC bf16, ~136.3 MB

    hipMemsetAsync(s_glob, 0, 16 * 16 * sizeof(float), stream);

    dc_k0_zeroborder<<<32, 256, 0, stream>>>(x_t);
    dc_k1_stage_attn<<<dim3(256, 16), 256, 0, stream>>>(x, att_w1, att_b1, s_glob, x_t);
    dc_k2a_softmax_bias<<<1, 64, 0, stream>>>(s_glob, att_w2, att_b2, b_bank, pi, b_agg);
    dc_k2b_aggw<<<dim3(64, 16), 64, 0, stream>>>(w_bank, pi, A_frag);
    dc_k3_conv<<<256, 512, 0, stream>>>(x_t, A_frag, b_agg, out);
}